// Round 11
// baseline (27.140 us; speedup 1.0000x reference)
//
#include <hip/hip_runtime.h>

typedef __attribute__((ext_vector_type(8))) short bf16x8;
typedef __attribute__((ext_vector_type(4))) float f32x4;

#define NPART   2048
#define NCOMP   8192
#define NBATCH  8
#define THRESH  0.05f
#define FLTMAX  3.4028235e38f

#define WAVES   16
#define PTSBLK  256
#define ATILES  (PTSBLK / 16)              // 16 A-tiles per block
#define BT      8                          // B-tiles per wave = 128 partials
#define BLKSPB  (NCOMP / PTSBLK)           // 32 blocks per batch
#define GRID    (NBATCH * BLKSPB)          // 256 blocks

// ws layout: Aenc 65536 pts x 16 B = 1 MiB; Benc 16384 x 32 B = 512 KiB; slots
#define BENC_OFF ((size_t)NBATCH * NCOMP * 16)
#define SLOT_OFF (BENC_OFF + (size_t)NBATCH * NPART * 32)

__device__ __forceinline__ unsigned short bf16rne(float x) {
    unsigned int b = __float_as_uint(x);
    return (unsigned short)((b + 0x7FFFu + ((b >> 16) & 1u)) >> 16);
}
__device__ __forceinline__ float bf16tof(unsigned short h) {
    return __uint_as_float(((unsigned int)h) << 16);
}

// Encode both operands once.
// A row k0..7  = [chx,chy,chz, clx,cly,clz, chx,chy]   (k8..10 = [chz,1,1] built in-kernel)
// B col k0..15 = [qhx,qhy,qhz, qhx,qhy,qhz, qlx,qly, qlz, p2h, p2l, 0,0,0,0,0]  (q = -2p)
__global__ __launch_bounds__(256) void pml_prep(
    const float* __restrict__ completed,
    const float* __restrict__ partial,
    unsigned int* __restrict__ Aenc,      // uint4-ish via 32-bit words
    unsigned int* __restrict__ Benc)
{
    int i = blockIdx.x * 256 + threadIdx.x;
    if (i < NBATCH * NCOMP) {
        const float* p = completed + 3 * (size_t)i;
        float x = p[0], y = p[1], z = p[2];
        unsigned int hx = bf16rne(x), hy = bf16rne(y), hz = bf16rne(z);
        unsigned int lx = bf16rne(x - bf16tof(hx));
        unsigned int ly = bf16rne(y - bf16tof(hy));
        unsigned int lz = bf16rne(z - bf16tof(hz));
        uint4 o;
        o.x = hx | (hy << 16);
        o.y = hz | (lx << 16);
        o.z = ly | (lz << 16);
        o.w = hx | (hy << 16);
        ((uint4*)Aenc)[i] = o;
    } else {
        int j = i - NBATCH * NCOMP;
        if (j < NBATCH * NPART) {
            const float* p = partial + 3 * (size_t)j;
            float qx = -2.0f * p[0], qy = -2.0f * p[1], qz = -2.0f * p[2];
            float p2 = fmaf(p[0], p[0], fmaf(p[1], p[1], p[2] * p[2]));
            unsigned int qhx = bf16rne(qx), qhy = bf16rne(qy), qhz = bf16rne(qz);
            unsigned int qlx = bf16rne(qx - bf16tof(qhx));
            unsigned int qly = bf16rne(qy - bf16tof(qhy));
            unsigned int qlz = bf16rne(qz - bf16tof(qhz));
            unsigned int p2h = bf16rne(p2);
            unsigned int p2l = bf16rne(p2 - bf16tof(p2h));
            uint4 o0, o1;
            o0.x = qhx | (qhy << 16);
            o0.y = qhz | (qhx << 16);
            o0.z = qhy | (qhz << 16);
            o0.w = qlx | (qly << 16);
            o1.x = qlz | (p2h << 16);
            o1.y = p2l;              // k10=p2l, k11=0
            o1.z = 0u;
            o1.w = 0u;
            ((uint4*)Benc)[2 * j + 0] = o0;
            ((uint4*)Benc)[2 * j + 1] = o1;
        }
    }
}

// min over the 16 lanes of each DPP row via rotations (pure VALU, no LDS pipe)
__device__ __forceinline__ float rowmin16(float v) {
    int x = __float_as_int(v);
    v = fminf(v, __int_as_float(__builtin_amdgcn_update_dpp(x, x, 0x128, 0xF, 0xF, false)));
    x = __float_as_int(v);
    v = fminf(v, __int_as_float(__builtin_amdgcn_update_dpp(x, x, 0x124, 0xF, 0xF, false)));
    x = __float_as_int(v);
    v = fminf(v, __int_as_float(__builtin_amdgcn_update_dpp(x, x, 0x122, 0xF, 0xF, false)));
    x = __float_as_int(v);
    v = fminf(v, __int_as_float(__builtin_amdgcn_update_dpp(x, x, 0x121, 0xF, 0xF, false)));
    return v;
}

__global__ __launch_bounds__(1024, 4) void pml_main(
    const float* __restrict__ completed,
    const unsigned short* __restrict__ Aenc,
    const unsigned short* __restrict__ Benc,
    float2* __restrict__ slots_out)
{
    const int tid  = threadIdx.x;
    const int lane = tid & 63;
    const int wave = tid >> 6;            // 0..15, owns 128 partials
    const int g    = lane >> 4;           // k-group: k = g*8 + j
    const int lr   = lane & 15;           // A row / B col within tile
    const int batch = blockIdx.x >> 5;
    const int blkb  = blockIdx.x & (BLKSPB - 1);

    __shared__ float smin[PTSBLK][WAVES + 1];  // 17 KB, pitch 17 -> 2-way (free)
    __shared__ float        rs[4];
    __shared__ unsigned int rc[4];

    // ---- resident B-frags: this wave's 8 tiles (16 partials each) ----
    bf16x8 bfr[BT];
    const unsigned short* bbase =
        Benc + ((size_t)(batch * NPART + wave * 128)) * 16;
    #pragma unroll
    for (int t = 0; t < BT; ++t) {
        bf16x8 v = {};
        if (g < 2)
            v = *(const bf16x8*)(bbase + ((size_t)(t * 16 + lr)) * 16 + g * 8);
        bfr[t] = v;
    }

    const unsigned short* abase =
        Aenc + ((size_t)(batch * NCOMP + blkb * PTSBLK)) * 8;
    const f32x4 zero4 = {0.0f, 0.0f, 0.0f, 0.0f};
    const short ONE = (short)0x3F80;          // bf16 1.0

    // ---- sweep the block's 16 A-tiles ----
    for (int a = 0; a < ATILES; ++a) {
        bf16x8 af = {};
        if (g < 2) {
            bf16x8 t = *(const bf16x8*)(abase + ((size_t)(a * 16 + lr)) * 8);
            if (g == 0) {
                af = t;
            } else {                            // k8..15 = [chz, 1, 1, 0...]
                bf16x8 u = {};
                u[0] = t[2];
                u[1] = ONE;
                u[2] = ONE;
                af = u;
            }
        }

        f32x4 mac = {FLTMAX, FLTMAX, FLTMAX, FLTMAX};
        #pragma unroll
        for (int t = 0; t < BT; t += 2) {
            f32x4 d0 = __builtin_amdgcn_mfma_f32_16x16x32_bf16(af, bfr[t + 0], zero4, 0, 0, 0);
            f32x4 d1 = __builtin_amdgcn_mfma_f32_16x16x32_bf16(af, bfr[t + 1], zero4, 0, 0, 0);
            #pragma unroll
            for (int q = 0; q < 4; ++q)
                mac[q] = fminf(fminf(mac[q], d0[q]), d1[q]);   // v_min3
        }

        // D[r][c]: c = lr, r = g*4+q -> min over c = rowmin16, then one write
        #pragma unroll
        for (int q = 0; q < 4; ++q) {
            float m = rowmin16(mac[q]);
            if (lr == 0)
                smin[a * 16 + g * 4 + q][wave] = m;   // banks 4 apart: free
        }
    }
    __syncthreads();

    // ---- combine 16 wave-minima per point, +c2 (exact f32), mask, reduce ----
    float        v = 0.0f;
    unsigned int c = 0u;
    if (tid < PTSBLK) {
        float t = smin[tid][0];
        #pragma unroll
        for (int g2 = 1; g2 < WAVES; ++g2) t = fminf(t, smin[tid][g2]);
        const float* cp = completed + ((size_t)(batch * NCOMP + blkb * PTSBLK + tid)) * 3;
        float x = cp[0], y = cp[1], z = cp[2];
        float c2 = fmaf(x, x, fmaf(y, y, z * z));
        float m = fmaxf(c2 + t, 0.0f);
        if (m < THRESH) { v = m; c = 1u; }
        #pragma unroll
        for (int off = 32; off >= 1; off >>= 1) {
            v += __shfl_down(v, off, 64);
            c += __shfl_down(c, off, 64);
        }
        if ((tid & 63) == 0) { rs[tid >> 6] = v; rc[tid >> 6] = c; }
    }
    __syncthreads();
    if (tid == 0) {
        float        bs = 0.0f;
        unsigned int bc = 0u;
        #pragma unroll
        for (int w = 0; w < PTSBLK / 64; ++w) { bs += rs[w]; bc += rc[w]; }
        slots_out[blockIdx.x] = make_float2(bs, (float)bc);
    }
}

__global__ __launch_bounds__(256) void pml_fin(
    const float2* __restrict__ slots_in,
    float* __restrict__ out)
{
    const int tid = threadIdx.x;
    float2 sl = slots_in[tid];               // GRID == 256 == blockDim
    float s = sl.x, c = sl.y;
    #pragma unroll
    for (int off = 32; off >= 1; off >>= 1) {
        s += __shfl_down(s, off, 64);
        c += __shfl_down(c, off, 64);
    }
    __shared__ float ss[4], sc[4];
    if ((tid & 63) == 0) { ss[tid >> 6] = s; sc[tid >> 6] = c; }
    __syncthreads();
    if (tid == 0) {
        float s2 = ss[0] + ss[1] + ss[2] + ss[3];
        float c2 = sc[0] + sc[1] + sc[2] + sc[3];
        *out = (c2 > 0.0f) ? (s2 / (c2 + 1e-6f)) : 0.0f;   // WEIGHT = 1.0
    }
}

extern "C" void kernel_launch(void* const* d_in, const int* in_sizes, int n_in,
                              void* d_out, int out_size, void* d_ws, size_t ws_size,
                              hipStream_t stream) {
    const float* completed = (const float*)d_in[0];  // (8, 8192, 3) f32
    const float* partial   = (const float*)d_in[1];  // (8, 2048, 3) f32
    float* out = (float*)d_out;

    unsigned int*   AencW = (unsigned int*)d_ws;
    unsigned int*   BencW = (unsigned int*)((char*)d_ws + BENC_OFF);
    float2*         slots = (float2*)((char*)d_ws + SLOT_OFF);

    // 65536 A-points + 16384 B-points = 81920 threads
    pml_prep<<<dim3(320), dim3(256), 0, stream>>>(completed, partial, AencW, BencW);
    pml_main<<<dim3(GRID), dim3(1024), 0, stream>>>(
        completed, (const unsigned short*)AencW, (const unsigned short*)BencW, slots);
    pml_fin<<<dim3(1), dim3(256), 0, stream>>>(slots, out);
}

// Round 12
// 21.807 us; speedup vs baseline: 1.2446x; 1.2446x over previous
//
#include <hip/hip_runtime.h>

typedef __attribute__((ext_vector_type(8))) short bf16x8;
typedef __attribute__((ext_vector_type(4))) float f32x4;

#define NPART   2048
#define NCOMP   8192
#define NBATCH  8
#define THRESH  0.05f
#define FLTMAX  3.4028235e38f

#define WAVES   16
#define PTSBLK  256
#define ATILES  (PTSBLK / 16)              // 16 A-tiles per block
#define BT      8                          // B-tiles per wave = 128 partials
#define BLKSPB  (NCOMP / PTSBLK)           // 32 blocks per batch
#define GRID    (NBATCH * BLKSPB)          // 256 blocks

__device__ __forceinline__ unsigned int bf16rne(float x) {
    unsigned int b = __float_as_uint(x);
    return (b + 0x7FFFu + ((b >> 16) & 1u)) >> 16;
}
__device__ __forceinline__ float bf16tof(unsigned int h) {
    return __uint_as_float(h << 16);
}

// min over the 16 lanes of each DPP row via rotations (pure VALU, no LDS pipe)
__device__ __forceinline__ float rowmin16(float v) {
    int x = __float_as_int(v);
    v = fminf(v, __int_as_float(__builtin_amdgcn_update_dpp(x, x, 0x128, 0xF, 0xF, false)));
    x = __float_as_int(v);
    v = fminf(v, __int_as_float(__builtin_amdgcn_update_dpp(x, x, 0x124, 0xF, 0xF, false)));
    x = __float_as_int(v);
    v = fminf(v, __int_as_float(__builtin_amdgcn_update_dpp(x, x, 0x122, 0xF, 0xF, false)));
    x = __float_as_int(v);
    v = fminf(v, __int_as_float(__builtin_amdgcn_update_dpp(x, x, 0x121, 0xF, 0xF, false)));
    return v;
}

// Split-precision bf16 MFMA encoding (verified absmax=0 in R11):
// A row k0..15 = [chx,chy,chz, clx,cly,clz, chx,chy, chz, 1, 1, 0...]
// B col k0..15 = [qhx,qhy,qhz, qhx,qhy,qhz, qlx,qly, qlz, p2h, p2l, 0...]
// dot = (ch+cl).qh + ch.ql + p2  ~=  -2 c.p + |p|^2   (err ~3e-5)
__global__ __launch_bounds__(1024, 4) void pml_main(
    const float* __restrict__ completed,
    const float* __restrict__ partial,
    float2* __restrict__ slots_out)
{
    const int tid  = threadIdx.x;
    const int lane = tid & 63;
    const int wave = tid >> 6;            // 0..15, owns 128 partials
    const int g    = lane >> 4;           // k-group: k = g*8 + j
    const int lr   = lane & 15;           // A row / B col within tile
    const int batch = blockIdx.x >> 5;
    const int blkb  = blockIdx.x & (BLKSPB - 1);

    __shared__ unsigned int sB[WAVES][64][8];   // 32 KB rotating B-encodings
    __shared__ uint4        sA[PTSBLK];         // 4 KB A-encodings
    __shared__ float smin[PTSBLK][WAVES + 1];   // 17 KB, pitch 17
    __shared__ float        rs[4];
    __shared__ unsigned int rc[4];

    // ---- in-kernel A-encode: block's 256 completed points (no prep kernel) ----
    const size_t cbase = ((size_t)batch * NCOMP + (size_t)blkb * PTSBLK) * 3;
    if (tid < PTSBLK) {
        const float* p = completed + cbase + 3 * tid;
        float x = p[0], y = p[1], z = p[2];
        unsigned int hx = bf16rne(x), hy = bf16rne(y), hz = bf16rne(z);
        unsigned int lx = bf16rne(x - bf16tof(hx));
        unsigned int ly = bf16rne(y - bf16tof(hy));
        unsigned int lz = bf16rne(z - bf16tof(hz));
        uint4 o;
        o.x = hx | (hy << 16);
        o.y = hz | (lx << 16);
        o.z = ly | (lz << 16);
        o.w = hx | (hy << 16);
        sA[tid] = o;
    }

    // ---- in-kernel B-encode: wave's 128 partials in two 64-pt phases ----
    // Same-wave LDS write->read (in-order pipe): no cross-wave deps, no barrier.
    bf16x8 bfr[BT];
    const float* pb = partial + ((size_t)batch * NPART + (size_t)wave * 128) * 3;
    #pragma unroll
    for (int h = 0; h < 2; ++h) {
        const float* pp = pb + 3 * (h * 64 + lane);
        float px = pp[0], py = pp[1], pz = pp[2];
        float qx = -2.0f * px, qy = -2.0f * py, qz = -2.0f * pz;
        float p2 = fmaf(px, px, fmaf(py, py, pz * pz));
        unsigned int qhx = bf16rne(qx), qhy = bf16rne(qy), qhz = bf16rne(qz);
        unsigned int qlx = bf16rne(qx - bf16tof(qhx));
        unsigned int qly = bf16rne(qy - bf16tof(qhy));
        unsigned int qlz = bf16rne(qz - bf16tof(qhz));
        unsigned int p2h = bf16rne(p2);
        unsigned int p2l = bf16rne(p2 - bf16tof(p2h));
        uint4 o0, o1;
        o0.x = qhx | (qhy << 16);
        o0.y = qhz | (qhx << 16);
        o0.z = qhy | (qhz << 16);
        o0.w = qlx | (qly << 16);
        o1.x = qlz | (p2h << 16);
        o1.y = p2l;
        o1.z = 0u;
        o1.w = 0u;
        *(uint4*)&sB[wave][lane][0] = o0;
        *(uint4*)&sB[wave][lane][4] = o1;
        // read this half's 4 tiles of B-frags (one-time, conflicts acceptable)
        #pragma unroll
        for (int tt = 0; tt < 4; ++tt) {
            bf16x8 v = {};
            if (g < 2)
                v = *(const bf16x8*)((const unsigned short*)&sB[wave][tt * 16 + lr][0] + g * 8);
            bfr[h * 4 + tt] = v;
        }
    }

    __syncthreads();   // sA visible to all waves

    const f32x4 zero4 = {0.0f, 0.0f, 0.0f, 0.0f};
    const short ONE = (short)0x3F80;          // bf16 1.0

    // ---- sweep the block's 16 A-tiles (verified R11 core) ----
    for (int a = 0; a < ATILES; ++a) {
        bf16x8 af = {};
        if (g < 2) {
            bf16x8 t = *(const bf16x8*)&sA[a * 16 + lr];
            if (g == 0) {
                af = t;
            } else {                            // k8..15 = [chz, 1, 1, 0...]
                bf16x8 u = {};
                u[0] = t[2];
                u[1] = ONE;
                u[2] = ONE;
                af = u;
            }
        }

        f32x4 mac = {FLTMAX, FLTMAX, FLTMAX, FLTMAX};
        #pragma unroll
        for (int t = 0; t < BT; t += 2) {
            f32x4 d0 = __builtin_amdgcn_mfma_f32_16x16x32_bf16(af, bfr[t + 0], zero4, 0, 0, 0);
            f32x4 d1 = __builtin_amdgcn_mfma_f32_16x16x32_bf16(af, bfr[t + 1], zero4, 0, 0, 0);
            #pragma unroll
            for (int q = 0; q < 4; ++q)
                mac[q] = fminf(fminf(mac[q], d0[q]), d1[q]);   // v_min3
        }

        // D[r][c]: c = lr, r = g*4+q -> min over c = rowmin16, then one write
        #pragma unroll
        for (int q = 0; q < 4; ++q) {
            float m = rowmin16(mac[q]);
            if (lr == 0)
                smin[a * 16 + g * 4 + q][wave] = m;
        }
    }
    __syncthreads();

    // ---- combine 16 wave-minima per point, +c2 (exact f32), mask, reduce ----
    float        v = 0.0f;
    unsigned int c = 0u;
    if (tid < PTSBLK) {
        float t = smin[tid][0];
        #pragma unroll
        for (int g2 = 1; g2 < WAVES; ++g2) t = fminf(t, smin[tid][g2]);
        const float* cp = completed + cbase + 3 * tid;
        float x = cp[0], y = cp[1], z = cp[2];
        float c2 = fmaf(x, x, fmaf(y, y, z * z));
        float m = fmaxf(c2 + t, 0.0f);
        if (m < THRESH) { v = m; c = 1u; }
        #pragma unroll
        for (int off = 32; off >= 1; off >>= 1) {
            v += __shfl_down(v, off, 64);
            c += __shfl_down(c, off, 64);
        }
        if ((tid & 63) == 0) { rs[tid >> 6] = v; rc[tid >> 6] = c; }
    }
    __syncthreads();
    if (tid == 0) {
        float        bs = 0.0f;
        unsigned int bc = 0u;
        #pragma unroll
        for (int w = 0; w < PTSBLK / 64; ++w) { bs += rs[w]; bc += rc[w]; }
        slots_out[blockIdx.x] = make_float2(bs, (float)bc);
    }
}

__global__ __launch_bounds__(256) void pml_fin(
    const float2* __restrict__ slots_in,
    float* __restrict__ out)
{
    const int tid = threadIdx.x;
    float2 sl = slots_in[tid];               // GRID == 256 == blockDim
    float s = sl.x, c = sl.y;
    #pragma unroll
    for (int off = 32; off >= 1; off >>= 1) {
        s += __shfl_down(s, off, 64);
        c += __shfl_down(c, off, 64);
    }
    __shared__ float ss[4], sc[4];
    if ((tid & 63) == 0) { ss[tid >> 6] = s; sc[tid >> 6] = c; }
    __syncthreads();
    if (tid == 0) {
        float s2 = ss[0] + ss[1] + ss[2] + ss[3];
        float c2 = sc[0] + sc[1] + sc[2] + sc[3];
        *out = (c2 > 0.0f) ? (s2 / (c2 + 1e-6f)) : 0.0f;   // WEIGHT = 1.0
    }
}

extern "C" void kernel_launch(void* const* d_in, const int* in_sizes, int n_in,
                              void* d_out, int out_size, void* d_ws, size_t ws_size,
                              hipStream_t stream) {
    const float* completed = (const float*)d_in[0];  // (8, 8192, 3) f32
    const float* partial   = (const float*)d_in[1];  // (8, 2048, 3) f32
    float* out = (float*)d_out;
    float2* slots = (float2*)d_ws;                   // 256 slots, all written
                                                     // before fin reads them:
                                                     // no memset node needed

    pml_main<<<dim3(GRID), dim3(1024), 0, stream>>>(completed, partial, slots);
    pml_fin<<<dim3(1), dim3(256), 0, stream>>>(slots, out);
}